// Round 1
// baseline (2106.010 us; speedup 1.0000x reference)
//
#include <hip/hip_runtime.h>

// Problem constants
#define BB 8
#define TT 2048
#define CC 32
#define HH 2048
#define SCALE 0.17677669529663687f  // 1/sqrt(32)

typedef _Float16 f16;
typedef f16 f16x8 __attribute__((ext_vector_type(8)));
typedef float f32x4 __attribute__((ext_vector_type(4)));

// ---------------- K1: q/k/v projections (fp32 in, fp16 out) ----------------
__global__ __launch_bounds__(256) void proj_kernel(
    const float* __restrict__ x, const float* __restrict__ Wk,
    const float* __restrict__ Wq, const float* __restrict__ Wv,
    f16* __restrict__ qh, f16* __restrict__ kh, f16* __restrict__ vh)
{
    __shared__ float xs[8][CC];
    const int tid = threadIdx.x;
    const size_t rbase = (size_t)blockIdx.x * 8;   // global row in [0, B*T)
    xs[tid >> 5][tid & 31] = x[rbase * CC + tid];
    __syncthreads();

    const float* W[3] = {Wq, Wk, Wv};
    f16* O[3] = {qh, kh, vh};
    #pragma unroll
    for (int m = 0; m < 3; m++) {
        for (int h = tid; h < HH; h += 256) {
            float w[CC];
            #pragma unroll
            for (int c = 0; c < CC; c++) w[c] = W[m][(size_t)c * HH + h];
            #pragma unroll
            for (int r = 0; r < 8; r++) {
                float acc = 0.f;
                #pragma unroll
                for (int c = 0; c < CC; c++) acc += xs[r][c] * w[c];
                O[m][(rbase + r) * HH + h] = (f16)acc;
            }
        }
    }
}

// ---------- K2: scores + causal softmax (two-pass, writes p = e/l) ----------
// Block: 256 threads (4 waves), one (batch, 64-row q-tile). Triangular s-loop.
__global__ __launch_bounds__(256) void qk_softmax_kernel(
    const f16* __restrict__ qh, const f16* __restrict__ kh,
    f16* __restrict__ attn)
{
    const int b = blockIdx.y;
    const int qt = blockIdx.x;            // q tile (64 rows)
    const int tid = threadIdx.x;
    const int wave = tid >> 6, lane = tid & 63;
    const int g = lane >> 4, li = lane & 15;

    __shared__ f16 qs[64][72];            // 144 B row stride: 16B-aligned, 2-way banks
    __shared__ f16 ks[64][72];

    const f16* qp = qh + (size_t)b * TT * HH;
    const f16* kp = kh + (size_t)b * TT * HH;
    f16* ap = attn + (size_t)b * TT * TT;
    const int tbase = qt * 64;
    const int myrow0 = wave * 16 + g * 4; // local row of acc reg 0

    float m[4], l[4];
    #pragma unroll
    for (int r = 0; r < 4; r++) { m[r] = -1e30f; l[r] = 0.f; }

    for (int pass = 0; pass < 2; pass++) {
        for (int st = 0; st <= qt; st++) {
            const int sbase = st * 64;
            f32x4 acc[4] = {};
            for (int hc = 0; hc < HH; hc += 64) {
                __syncthreads();
                #pragma unroll
                for (int i = 0; i < 2; i++) {
                    int idx = tid + i * 256;
                    int rr = idx >> 3, c8 = (idx & 7) * 8;
                    *(f16x8*)&qs[rr][c8] =
                        *(const f16x8*)&qp[(size_t)(tbase + rr) * HH + hc + c8];
                    *(f16x8*)&ks[rr][c8] =
                        *(const f16x8*)&kp[(size_t)(sbase + rr) * HH + hc + c8];
                }
                __syncthreads();
                #pragma unroll
                for (int kk = 0; kk < 2; kk++) {
                    f16x8 af = *(const f16x8*)&qs[wave * 16 + li][kk * 32 + g * 8];
                    #pragma unroll
                    for (int n = 0; n < 4; n++) {
                        f16x8 bf = *(const f16x8*)&ks[n * 16 + li][kk * 32 + g * 8];
                        acc[n] = __builtin_amdgcn_mfma_f32_16x16x32_f16(af, bf, acc[n], 0, 0, 0);
                    }
                }
            }
            if (pass == 0) {
                // online m,l update (registers only; all 16 lanes of a group redundant)
                #pragma unroll
                for (int r = 0; r < 4; r++) {
                    const int row = tbase + myrow0 + r;
                    float sv[4], tmax = -1e30f;
                    #pragma unroll
                    for (int n = 0; n < 4; n++) {
                        int col = sbase + n * 16 + li;
                        sv[n] = (col <= row) ? acc[n][r] * SCALE : -1e30f;
                        tmax = fmaxf(tmax, sv[n]);
                    }
                    #pragma unroll
                    for (int off = 1; off < 16; off <<= 1)
                        tmax = fmaxf(tmax, __shfl_xor(tmax, off, 64));
                    float mn = fmaxf(m[r], tmax);
                    float s0 = 0.f;
                    #pragma unroll
                    for (int n = 0; n < 4; n++) s0 += __expf(sv[n] - mn);
                    #pragma unroll
                    for (int off = 1; off < 16; off <<= 1)
                        s0 += __shfl_xor(s0, off, 64);
                    l[r] = l[r] * __expf(m[r] - mn) + s0;
                    m[r] = mn;
                }
            } else {
                #pragma unroll
                for (int r = 0; r < 4; r++) {
                    const int row = tbase + myrow0 + r;
                    const float inv = 1.f / l[r];
                    #pragma unroll
                    for (int n = 0; n < 4; n++) {
                        int col = sbase + n * 16 + li;
                        float p = (col <= row)
                                    ? __expf(acc[n][r] * SCALE - m[r]) * inv : 0.f;
                        ap[(size_t)row * TT + col] = (f16)p;
                    }
                }
            }
        }
    }
}

// ---------------- K3: out = attn @ v (triangular K-loop) ----------------
__global__ __launch_bounds__(256) void pv_kernel(
    const f16* __restrict__ attn, const f16* __restrict__ vh,
    float* __restrict__ out)
{
    const int b = blockIdx.z;
    const int qt = blockIdx.y;
    const int ht = blockIdx.x;
    const int tid = threadIdx.x;
    const int wave = tid >> 6, lane = tid & 63, g = lane >> 4, li = lane & 15;

    __shared__ f16 as[64][72];
    __shared__ f16 vt[64][72];            // vt[h_local][s_local] (transposed V)

    const f16* ap = attn + (size_t)b * TT * TT;
    const f16* vp = vh + (size_t)b * TT * HH;
    const int tbase = qt * 64, hbase = ht * 64;

    f32x4 acc[4] = {};
    for (int st = 0; st <= qt; st++) {
        const int sbase = st * 64;
        __syncthreads();
        #pragma unroll
        for (int i = 0; i < 2; i++) {
            int idx = tid + i * 256;
            int rr = idx >> 3, c8 = (idx & 7) * 8;
            *(f16x8*)&as[rr][c8] =
                *(const f16x8*)&ap[(size_t)(tbase + rr) * TT + sbase + c8];
            f16x8 vv = *(const f16x8*)&vp[(size_t)(sbase + rr) * HH + hbase + c8];
            #pragma unroll
            for (int j = 0; j < 8; j++) vt[c8 + j][rr] = vv[j];
        }
        __syncthreads();
        #pragma unroll
        for (int kk = 0; kk < 2; kk++) {
            f16x8 af = *(const f16x8*)&as[wave * 16 + li][kk * 32 + g * 8];
            #pragma unroll
            for (int n = 0; n < 4; n++) {
                f16x8 bf = *(const f16x8*)&vt[n * 16 + li][kk * 32 + g * 8];
                acc[n] = __builtin_amdgcn_mfma_f32_16x16x32_f16(af, bf, acc[n], 0, 0, 0);
            }
        }
    }

    float* op = out + (size_t)b * TT * HH;
    const int grow = tbase + wave * 16 + g * 4;
    #pragma unroll
    for (int n = 0; n < 4; n++) {
        #pragma unroll
        for (int r = 0; r < 4; r++)
            op[(size_t)(grow + r) * HH + hbase + n * 16 + li] = acc[n][r];
    }
}

extern "C" void kernel_launch(void* const* d_in, const int* in_sizes, int n_in,
                              void* d_out, int out_size, void* d_ws, size_t ws_size,
                              hipStream_t stream) {
    const float* x  = (const float*)d_in[0];
    const float* Wk = (const float*)d_in[1];
    const float* Wq = (const float*)d_in[2];
    const float* Wv = (const float*)d_in[3];
    float* out = (float*)d_out;

    const size_t NE = (size_t)BB * TT * HH;  // 33.5M elements
    f16* qh   = (f16*)d_ws;
    f16* kh   = qh + NE;
    f16* vh   = kh + NE;
    f16* attn = vh + NE;                      // B*T*T fp16 — total 256 MiB

    proj_kernel<<<dim3((BB * TT) / 8), 256, 0, stream>>>(x, Wk, Wq, Wv, qh, kh, vh);
    qk_softmax_kernel<<<dim3(TT / 64, BB), 256, 0, stream>>>(qh, kh, attn);
    pv_kernel<<<dim3(HH / 64, TT / 64, BB), 256, 0, stream>>>(attn, vh, out);
}